// Round 1
// baseline (1108.774 us; speedup 1.0000x reference)
//
#include <hip/hip_runtime.h>
#include <hip/hip_fp16.h>

#define N_NODES 100000
#define N_EDGES 3200000
#define OUT_DIM 176
#define LN_EPS 1e-5f

typedef _Float16 h2 __attribute__((ext_vector_type(2)));

// Bucket sort parameters: bucket = row >> 9 (512 rows/bucket)
#define NBUCK 196
#define PC_BLOCKS 512
#define PC_CHUNK (N_EDGES / PC_BLOCKS)  // 6250
#define BP_CHUNK 4096
#define BP_BLOCKS ((N_EDGES + BP_CHUNK - 1) / BP_CHUNK)  // 782

// ---------------------------------------------------------------------------
// out[:, 0:64] = emb (fp32) AND emb_h = fp16(emb).
__global__ __launch_bounds__(256) void convert_emb_kernel(
    const float* __restrict__ emb, float* __restrict__ out,
    __half* __restrict__ emb_h) {
  int t = blockIdx.x * blockDim.x + threadIdx.x;
  if (t < N_NODES * 16) {
    int n = t >> 4, q = t & 15;
    float4 v = ((const float4*)emb)[t];
    ((float4*)out)[n * 44 + q] = v;
    __half2 a = __floats2half2_rn(v.x, v.y);
    __half2 b = __floats2half2_rn(v.z, v.w);
    uint2 u;
    u.x = *(unsigned int*)&a;
    u.y = *(unsigned int*)&b;
    ((uint2*)emb_h)[t] = u;
  }
}

// ---------------------------------------------------------------------------
// Weight prep: wt[j*DIN+i] = (half)w[i*DOUT+j]  (transposed, fp16).
__global__ __launch_bounds__(256) void wprep_kernel(
    const float* __restrict__ w1, const float* __restrict__ w2,
    __half* __restrict__ wt1, __half* __restrict__ wt2, int din, int dout) {
  int idx = blockIdx.x * 256 + threadIdx.x;
  if (idx < din * dout) {
    int i = idx / dout, j = idx % dout;
    wt1[j * din + i] = __float2half(w1[idx]);
    wt2[j * din + i] = __float2half(w2[idx]);
  }
}

// ---------------------------------------------------------------------------
// Pass A: per-bucket edge counts.
__global__ __launch_bounds__(256) void precount_kernel(
    const int* __restrict__ rows, int* __restrict__ gcount) {
  __shared__ int hist[NBUCK];
  for (int i = threadIdx.x; i < NBUCK; i += 256) hist[i] = 0;
  __syncthreads();
  const int e0 = blockIdx.x * PC_CHUNK;
  for (int e = e0 + threadIdx.x; e < e0 + PC_CHUNK; e += 256) {
    const int r = __builtin_nontemporal_load(rows + e);
    atomicAdd(&hist[r >> 9], 1);
  }
  __syncthreads();
  for (int i = threadIdx.x; i < NBUCK; i += 256)
    if (hist[i]) atomicAdd(&gcount[i], hist[i]);
}

// Exclusive scan of bucket counts -> bucket_base[197], cursor copy.
__global__ __launch_bounds__(256) void bucket_scan_kernel(
    const int* __restrict__ gcount, int* __restrict__ bucket_base,
    int* __restrict__ bucket_cursor) {
  __shared__ int sA[256], sB[256];
  const int t = threadIdx.x;
  int v = (t < NBUCK) ? gcount[t] : 0;
  sA[t] = v;
  __syncthreads();
  int* src = sA;
  int* dst = sB;
  for (int off = 1; off < 256; off <<= 1) {
    dst[t] = src[t] + ((t >= off) ? src[t - off] : 0);
    __syncthreads();
    int* tmp = src; src = dst; dst = tmp;
  }
  if (t < NBUCK) {
    const int excl = src[t] - v;
    bucket_base[t] = excl;
    bucket_cursor[t] = excl;
  }
  if (t == 0) bucket_base[NBUCK] = N_EDGES;
}

// ---------------------------------------------------------------------------
// Pass B: bucket the edges.
__global__ __launch_bounds__(256) void bucket_pass_kernel(
    const int* __restrict__ rows, const int* __restrict__ cols,
    const float* __restrict__ vals, int* __restrict__ bucket_cursor,
    int2* __restrict__ bucketed) {
  __shared__ int cnt[NBUCK], cur[NBUCK], gbase[NBUCK];
  for (int i = threadIdx.x; i < NBUCK; i += 256) {
    cnt[i] = 0;
    cur[i] = 0;
  }
  __syncthreads();

  const int e0 = blockIdx.x * BP_CHUNK;
  int r_[16], c_[16];
  float v_[16];
#pragma unroll
  for (int k = 0; k < 16; ++k) {
    const int e = e0 + threadIdx.x + k * 256;
    if (e < N_EDGES) {
      r_[k] = rows[e];
      c_[k] = cols[e];
      v_[k] = vals[e];
      atomicAdd(&cnt[r_[k] >> 9], 1);
    } else {
      r_[k] = -1;
    }
  }
  __syncthreads();

  for (int i = threadIdx.x; i < NBUCK; i += 256)
    gbase[i] = cnt[i] ? atomicAdd(&bucket_cursor[i], cnt[i]) : 0;
  __syncthreads();

#pragma unroll
  for (int k = 0; k < 16; ++k) {
    if (r_[k] >= 0) {
      const int b = r_[k] >> 9;
      const int lp = atomicAdd(&cur[b], 1);
      const int meta = c_[k] | ((r_[k] & 511) << 17);
      bucketed[gbase[b] + lp] = make_int2(meta, __float_as_int(v_[k]));
    }
  }
}

// ---------------------------------------------------------------------------
// Pass C: one block per bucket -> row_ptr + exact CSR order.
__global__ __launch_bounds__(512) void csr_build_kernel(
    const int2* __restrict__ bucketed, const int* __restrict__ bucket_base,
    int* __restrict__ row_ptr, int2* __restrict__ packed) {
  __shared__ int hist[512], cur[512], sA[512], sB[512];
  const int t = threadIdx.x;
  const int blk = blockIdx.x;
  const int base = bucket_base[blk];
  const int n = bucket_base[blk + 1] - base;

  hist[t] = 0;
  __syncthreads();
  for (int i = t; i < n; i += 512) {
    const int rlow = bucketed[base + i].x >> 17;
    atomicAdd(&hist[rlow], 1);
  }
  __syncthreads();

  sA[t] = hist[t];
  __syncthreads();
  int* src = sA;
  int* dst = sB;
  for (int off = 1; off < 512; off <<= 1) {
    dst[t] = src[t] + ((t >= off) ? src[t - off] : 0);
    __syncthreads();
    int* tmp = src; src = dst; dst = tmp;
  }
  const int excl = src[t] - hist[t];

  const int row0 = blk << 9;
  if (row0 + t < N_NODES) row_ptr[row0 + t] = base + excl;
  if (blk == NBUCK - 1 && t == 0) row_ptr[N_NODES] = N_EDGES;
  cur[t] = excl;
  __syncthreads();

  for (int i = t; i < n; i += 512) {
    const int2 m = bucketed[base + i];
    const int rlow = m.x >> 17;
    const int col = m.x & 0x1FFFF;
    const int p = atomicAdd(&cur[rlow], 1);
    packed[base + p] = make_int2(col, m.y);
  }
}

// ---------------------------------------------------------------------------
// Gather SpMM, fp16 ego table — NO LDS. One wave per node.
template <int DIN>
__global__ __launch_bounds__(512) void spmm_kernel(
    const __half* __restrict__ ego_h, const int* __restrict__ row_ptr,
    const long long* __restrict__ packed, __half* __restrict__ side_out_h) {
  constexpr int LPH = DIN / 8;    // lanes per edge-row (16B fp16 chunks)
  constexpr int NGRP = 64 / LPH;  // edges concurrent

  const int lane = threadIdx.x & 63;
  const int li = lane % LPH;
  const int grp = lane / LPH;
  const int node = (blockIdx.x * blockDim.x + threadIdx.x) >> 6;
  if (node >= N_NODES) return;

  const uint4* __restrict__ ego8 = (const uint4*)ego_h;
  const int start = row_ptr[node];
  const int end = row_ptr[node + 1];

  float s[8] = {0.f, 0.f, 0.f, 0.f, 0.f, 0.f, 0.f, 0.f};

  for (int base = start; base < end; base += 64) {
    const int idx = base + lane;
    long long m = 0;  // col=0, val=0 padding contributes 0
    if (idx < end) m = __builtin_nontemporal_load(packed + idx);
    int mc = (int)m;
    int mv = (int)(m >> 32);
    const int cnt = min(end - base, 64);
    const int kmax = (cnt + NGRP - 1) / NGRP;
    for (int k = 0; k < kmax; ++k) {
      const int src = k * NGRP + grp;
      const int c = __shfl(mc, src, 64);
      const float v = __int_as_float(__shfl(mv, src, 64));
      uint4 raw = ego8[(long)c * LPH + li];
      const __half2* hp = (const __half2*)&raw;
      const float2 f0 = __half22float2(hp[0]);
      const float2 f1 = __half22float2(hp[1]);
      const float2 f2 = __half22float2(hp[2]);
      const float2 f3 = __half22float2(hp[3]);
      s[0] += v * f0.x; s[1] += v * f0.y;
      s[2] += v * f1.x; s[3] += v * f1.y;
      s[4] += v * f2.x; s[5] += v * f2.y;
      s[6] += v * f3.x; s[7] += v * f3.y;
    }
  }

#pragma unroll
  for (int mask = LPH; mask < 64; mask <<= 1) {
#pragma unroll
    for (int r = 0; r < 8; ++r) s[r] += __shfl_xor(s[r], mask, 64);
  }

  if (grp == 0) {
    __half2 p0 = __floats2half2_rn(s[0], s[1]);
    __half2 p1 = __floats2half2_rn(s[2], s[3]);
    __half2 p2 = __floats2half2_rn(s[4], s[5]);
    __half2 p3 = __floats2half2_rn(s[6], s[7]);
    uint4 u;
    u.x = *(unsigned int*)&p0;
    u.y = *(unsigned int*)&p1;
    u.z = *(unsigned int*)&p2;
    u.w = *(unsigned int*)&p3;
    ((uint4*)side_out_h)[(long)node * LPH + li] = u;
  }
}

// ---------------------------------------------------------------------------
// Dense + LN + l2norm.
// v2 (this round): latency-bound fix.
//  - __launch_bounds__(256,4): 128-VGPR budget so the 64 VGPRs of transposed
//    weights actually stay resident (v1 reported 52 VGPRs => compiler was
//    re-loading weights every node and serializing ego/side loads).
//  - software pipeline: next node's 16 uint4 loads issued right after the
//    dot phase, hidden under the LN/reduction epilogue.
//  - single-pass LN (sum + sumsq, var = E[x^2]-m^2): 4 interleaved shfl
//    chains, dependent depth 6 instead of 12; split dot accumulators (ILP).
template <int DIN, int DOUT, int COL_OFF>
__global__ __launch_bounds__(256, 4) void dense_kernel(
    const __half* __restrict__ ego_h, const __half* __restrict__ side_h,
    const __half* __restrict__ w1t, const float* __restrict__ b1,
    const __half* __restrict__ w2t, const float* __restrict__ b2,
    const float* __restrict__ g1, const float* __restrict__ be1,
    const float* __restrict__ g2, const float* __restrict__ be2,
    __half* __restrict__ ego_h_out, float* __restrict__ out) {
  constexpr int NPW = 64 / DOUT;
  constexpr int Q8 = DIN / 8;  // uint4 (8-half) chunks per row

  const int lane = threadIdx.x & 63;
  const int j = lane % DOUT;
  const int sub = lane / DOUT;

  // coalesced transposed-weight preload: row j = Q8 uint4s (resident)
  const uint4* __restrict__ w1u = (const uint4*)w1t;
  const uint4* __restrict__ w2u = (const uint4*)w2t;
  uint4 wraw1[Q8], wraw2[Q8];
#pragma unroll
  for (int q = 0; q < Q8; ++q) {
    wraw1[q] = w1u[j * Q8 + q];
    wraw2[q] = w2u[j * Q8 + q];
  }
  const float bb1 = b1[j], bb2 = b2[j];
  const float gg1 = g1[j], gg2 = g2[j];
  const float bbe1 = be1[j], bbe2 = be2[j];

  const uint4* __restrict__ ego8 = (const uint4*)ego_h;
  const uint4* __restrict__ side8 = (const uint4*)side_h;

  const int waveId = (blockIdx.x * blockDim.x + threadIdx.x) >> 6;
  const int nwaves = (gridDim.x * blockDim.x) >> 6;
  const int ngroups = N_NODES / NPW;

  uint4 eraw[Q8], sraw[Q8];
  int gidx = waveId;
  if (gidx < ngroups) {
    const int node0 = gidx * NPW + sub;
#pragma unroll
    for (int q = 0; q < Q8; ++q) {
      eraw[q] = ego8[node0 * Q8 + q];
      sraw[q] = side8[node0 * Q8 + q];
    }
  }

  for (; gidx < ngroups; gidx += nwaves) {
    const int node = gidx * NPW + sub;

    // --- dot phase: 4 independent accumulator chains ---
    float a1a = bb1, a1b = 0.f, a2a = bb2, a2b = 0.f;
#pragma unroll
    for (int q = 0; q < Q8; ++q) {
      const h2* e2 = (const h2*)&eraw[q];
      const h2* s2 = (const h2*)&sraw[q];
      const h2* wq1 = (const h2*)&wraw1[q];
      const h2* wq2 = (const h2*)&wraw2[q];
#pragma unroll
      for (int r = 0; r < 4; ++r) {
        const h2 xs = e2[r] + s2[r];
        const h2 xp = e2[r] * s2[r];
#if __has_builtin(__builtin_amdgcn_fdot2)
        if (q & 1) {
          a1b = __builtin_amdgcn_fdot2(xs, wq1[r], a1b, false);
          a2b = __builtin_amdgcn_fdot2(xp, wq2[r], a2b, false);
        } else {
          a1a = __builtin_amdgcn_fdot2(xs, wq1[r], a1a, false);
          a2a = __builtin_amdgcn_fdot2(xp, wq2[r], a2a, false);
        }
#else
        if (q & 1) {
          a1b += (float)xs.x * (float)wq1[r].x + (float)xs.y * (float)wq1[r].y;
          a2b += (float)xp.x * (float)wq2[r].x + (float)xp.y * (float)wq2[r].y;
        } else {
          a1a += (float)xs.x * (float)wq1[r].x + (float)xs.y * (float)wq1[r].y;
          a2a += (float)xp.x * (float)wq2[r].x + (float)xp.y * (float)wq2[r].y;
        }
#endif
      }
    }

    // --- prefetch next node (hidden under the reduction epilogue) ---
    const int gn = gidx + nwaves;
    if (gn < ngroups) {
      const int nn = gn * NPW + sub;
#pragma unroll
      for (int q = 0; q < Q8; ++q) {
        eraw[q] = ego8[nn * Q8 + q];
        sraw[q] = side8[nn * Q8 + q];
      }
    }

    const float acc1 = a1a + a1b;
    const float acc2 = a2a + a2b;
    const float h1 = acc1 > 0.f ? acc1 : 0.01f * acc1;
    const float h2v = acc2 > 0.f ? acc2 : 0.01f * acc2;

    // --- single-pass LN: 4 interleaved reduction chains, depth log2(DOUT) ---
    float s1 = h1, q1 = h1 * h1, s2 = h2v, q2 = h2v * h2v;
#pragma unroll
    for (int mask = DOUT / 2; mask > 0; mask >>= 1) {
      s1 += __shfl_xor(s1, mask, DOUT);
      q1 += __shfl_xor(q1, mask, DOUT);
      s2 += __shfl_xor(s2, mask, DOUT);
      q2 += __shfl_xor(q2, mask, DOUT);
    }
    const float m1 = s1 * (1.0f / DOUT);
    const float m2 = s2 * (1.0f / DOUT);
    const float v1 = fmaxf(q1 * (1.0f / DOUT) - m1 * m1, 0.f);
    const float v2 = fmaxf(q2 * (1.0f / DOUT) - m2 * m2, 0.f);
    const float sv = (h1 - m1) * rsqrtf(v1 + LN_EPS) * gg1 + bbe1;
    const float bv = (h2v - m2) * rsqrtf(v2 + LN_EPS) * gg2 + bbe2;
    const float en = sv + bv;

    float ss = en * en;
#pragma unroll
    for (int mask = DOUT / 2; mask > 0; mask >>= 1) {
      ss += __shfl_xor(ss, mask, DOUT);
    }
    const float ov = en / fmaxf(sqrtf(ss), 1e-12f);

    if (ego_h_out) ego_h_out[(long)node * DOUT + j] = __float2half(en);
    out[(long)node * OUT_DIM + COL_OFF + j] = ov;
  }
}

// ---------------------------------------------------------------------------
extern "C" void kernel_launch(void* const* d_in, const int* in_sizes, int n_in,
                              void* d_out, int out_size, void* d_ws,
                              size_t ws_size, hipStream_t stream) {
  const float* emb = (const float*)d_in[0];
  const int* rows = (const int*)d_in[1];
  const int* cols = (const int*)d_in[2];
  const float* vals = (const float*)d_in[3];

  const float* P[3][8];
  for (int k = 0; k < 3; ++k)
    for (int p = 0; p < 8; ++p) P[k][p] = (const float*)d_in[4 + 8 * k + p];

  float* out = (float*)d_out;

  char* ws = (char*)d_ws;
  int2* packed = (int2*)ws;                          // E*8   = 25.6 MB
  char* sideArea = ws + (size_t)N_EDGES * 8;         // 25.6 MB region
  __half* side_h = (__half*)sideArea;                // N*64*2 = 12.8 MB used
  int2* bucketed = (int2*)sideArea;  // ALIAS: dead before spmm writes side
  __half* emb_h = (__half*)(sideArea + (size_t)N_NODES * 64 * 4);  // 12.8 MB
  __half* ego1_h = emb_h + (size_t)N_NODES * 64;                   // 12.8 MB
  __half* ego2_h = ego1_h + (size_t)N_NODES * 64;                  // 6.4 MB
  // transposed fp16 weights (16B-aligned block)
  __half* wt1_0 = ego2_h + (size_t)N_NODES * 32;  // 4096 halves
  __half* wt2_0 = wt1_0 + 4096;
  __half* wt1_1 = wt2_0 + 4096;  // 2048
  __half* wt2_1 = wt1_1 + 2048;
  __half* wt1_2 = wt2_1 + 2048;  // 512
  __half* wt2_2 = wt1_2 + 512;
  int* row_ptr = (int*)(wt2_2 + 512);  // N+1
  int* gcount = row_ptr + (N_NODES + 1);
  int* bucket_base = gcount + NBUCK;
  int* bucket_cursor = bucket_base + (NBUCK + 1);

  // ---- CSR build via two-level bucket sort ----
  hipMemsetAsync(gcount, 0, NBUCK * sizeof(int), stream);
  precount_kernel<<<PC_BLOCKS, 256, 0, stream>>>(rows, gcount);
  bucket_scan_kernel<<<1, 256, 0, stream>>>(gcount, bucket_base,
                                            bucket_cursor);
  bucket_pass_kernel<<<BP_BLOCKS, 256, 0, stream>>>(rows, cols, vals,
                                                    bucket_cursor, bucketed);
  csr_build_kernel<<<NBUCK, 512, 0, stream>>>(bucketed, bucket_base, row_ptr,
                                              packed);

  // ---- weight prep (transposed fp16) ----
  wprep_kernel<<<16, 256, 0, stream>>>(P[0][0], P[0][2], wt1_0, wt2_0, 64, 64);
  wprep_kernel<<<8, 256, 0, stream>>>(P[1][0], P[1][2], wt1_1, wt2_1, 64, 32);
  wprep_kernel<<<2, 256, 0, stream>>>(P[2][0], P[2][2], wt1_2, wt2_2, 32, 16);

  convert_emb_kernel<<<(N_NODES * 16 + 255) / 256, 256, 0, stream>>>(emb, out,
                                                                     emb_h);

  const int SPMM_BLOCKS = (N_NODES + 7) / 8;  // wave/node, 512 threads
  const int DENSE_BLOCKS = 1024;  // 4 blocks/CU resident at 128-VGPR cap

  // ---- layer 0: 64 -> 64 ----
  spmm_kernel<64><<<SPMM_BLOCKS, 512, 0, stream>>>(
      emb_h, row_ptr, (const long long*)packed, side_h);
  dense_kernel<64, 64, 64><<<DENSE_BLOCKS, 256, 0, stream>>>(
      emb_h, side_h, wt1_0, P[0][1], wt2_0, P[0][3], P[0][4], P[0][5],
      P[0][6], P[0][7], ego1_h, out);

  // ---- layer 1: 64 -> 32 ----
  spmm_kernel<64><<<SPMM_BLOCKS, 512, 0, stream>>>(
      ego1_h, row_ptr, (const long long*)packed, side_h);
  dense_kernel<64, 32, 128><<<DENSE_BLOCKS, 256, 0, stream>>>(
      ego1_h, side_h, wt1_1, P[1][1], wt2_1, P[1][3], P[1][4], P[1][5],
      P[1][6], P[1][7], ego2_h, out);

  // ---- layer 2: 32 -> 16 ----
  spmm_kernel<32><<<SPMM_BLOCKS, 512, 0, stream>>>(
      ego2_h, row_ptr, (const long long*)packed, side_h);
  dense_kernel<32, 16, 160><<<DENSE_BLOCKS, 256, 0, stream>>>(
      ego2_h, side_h, wt1_2, P[2][1], wt2_2, P[2][3], P[2][4], P[2][5],
      P[2][6], P[2][7], nullptr, out);
}

// Round 2
// 542.813 us; speedup vs baseline: 2.0426x; 2.0426x over previous
//
#include <hip/hip_runtime.h>
#include <hip/hip_fp16.h>

#define N_NODES 100000
#define N_EDGES 3200000
#define OUT_DIM 176
#define LN_EPS 1e-5f

typedef _Float16 h2 __attribute__((ext_vector_type(2)));

// Bucket sort parameters: bucket = row >> 9 (512 rows/bucket)
#define NBUCK 196
#define PC_BLOCKS 512
#define PC_CHUNK (N_EDGES / PC_BLOCKS)  // 6250
#define BP_CHUNK 4096
#define BP_BLOCKS ((N_EDGES + BP_CHUNK - 1) / BP_CHUNK)  // 782

// ---------------------------------------------------------------------------
// out[:, 0:64] = emb (fp32) AND emb_h = fp16(emb).
__global__ __launch_bounds__(256) void convert_emb_kernel(
    const float* __restrict__ emb, float* __restrict__ out,
    __half* __restrict__ emb_h) {
  int t = blockIdx.x * blockDim.x + threadIdx.x;
  if (t < N_NODES * 16) {
    int n = t >> 4, q = t & 15;
    float4 v = ((const float4*)emb)[t];
    ((float4*)out)[n * 44 + q] = v;
    __half2 a = __floats2half2_rn(v.x, v.y);
    __half2 b = __floats2half2_rn(v.z, v.w);
    uint2 u;
    u.x = *(unsigned int*)&a;
    u.y = *(unsigned int*)&b;
    ((uint2*)emb_h)[t] = u;
  }
}

// ---------------------------------------------------------------------------
// Weight prep: wt[j*DIN+i] = (half)w[i*DOUT+j]  (transposed, fp16).
__global__ __launch_bounds__(256) void wprep_kernel(
    const float* __restrict__ w1, const float* __restrict__ w2,
    __half* __restrict__ wt1, __half* __restrict__ wt2, int din, int dout) {
  int idx = blockIdx.x * 256 + threadIdx.x;
  if (idx < din * dout) {
    int i = idx / dout, j = idx % dout;
    wt1[j * din + i] = __float2half(w1[idx]);
    wt2[j * din + i] = __float2half(w2[idx]);
  }
}

// ---------------------------------------------------------------------------
// Pass A: per-bucket edge counts.
__global__ __launch_bounds__(256) void precount_kernel(
    const int* __restrict__ rows, int* __restrict__ gcount) {
  __shared__ int hist[NBUCK];
  for (int i = threadIdx.x; i < NBUCK; i += 256) hist[i] = 0;
  __syncthreads();
  const int e0 = blockIdx.x * PC_CHUNK;
  for (int e = e0 + threadIdx.x; e < e0 + PC_CHUNK; e += 256) {
    const int r = __builtin_nontemporal_load(rows + e);
    atomicAdd(&hist[r >> 9], 1);
  }
  __syncthreads();
  for (int i = threadIdx.x; i < NBUCK; i += 256)
    if (hist[i]) atomicAdd(&gcount[i], hist[i]);
}

// Exclusive scan of bucket counts -> bucket_base[197], cursor copy.
__global__ __launch_bounds__(256) void bucket_scan_kernel(
    const int* __restrict__ gcount, int* __restrict__ bucket_base,
    int* __restrict__ bucket_cursor) {
  __shared__ int sA[256], sB[256];
  const int t = threadIdx.x;
  int v = (t < NBUCK) ? gcount[t] : 0;
  sA[t] = v;
  __syncthreads();
  int* src = sA;
  int* dst = sB;
  for (int off = 1; off < 256; off <<= 1) {
    dst[t] = src[t] + ((t >= off) ? src[t - off] : 0);
    __syncthreads();
    int* tmp = src; src = dst; dst = tmp;
  }
  if (t < NBUCK) {
    const int excl = src[t] - v;
    bucket_base[t] = excl;
    bucket_cursor[t] = excl;
  }
  if (t == 0) bucket_base[NBUCK] = N_EDGES;
}

// ---------------------------------------------------------------------------
// Pass B: bucket the edges.
__global__ __launch_bounds__(256) void bucket_pass_kernel(
    const int* __restrict__ rows, const int* __restrict__ cols,
    const float* __restrict__ vals, int* __restrict__ bucket_cursor,
    int2* __restrict__ bucketed) {
  __shared__ int cnt[NBUCK], cur[NBUCK], gbase[NBUCK];
  for (int i = threadIdx.x; i < NBUCK; i += 256) {
    cnt[i] = 0;
    cur[i] = 0;
  }
  __syncthreads();

  const int e0 = blockIdx.x * BP_CHUNK;
  int r_[16], c_[16];
  float v_[16];
#pragma unroll
  for (int k = 0; k < 16; ++k) {
    const int e = e0 + threadIdx.x + k * 256;
    if (e < N_EDGES) {
      r_[k] = rows[e];
      c_[k] = cols[e];
      v_[k] = vals[e];
      atomicAdd(&cnt[r_[k] >> 9], 1);
    } else {
      r_[k] = -1;
    }
  }
  __syncthreads();

  for (int i = threadIdx.x; i < NBUCK; i += 256)
    gbase[i] = cnt[i] ? atomicAdd(&bucket_cursor[i], cnt[i]) : 0;
  __syncthreads();

#pragma unroll
  for (int k = 0; k < 16; ++k) {
    if (r_[k] >= 0) {
      const int b = r_[k] >> 9;
      const int lp = atomicAdd(&cur[b], 1);
      const int meta = c_[k] | ((r_[k] & 511) << 17);
      bucketed[gbase[b] + lp] = make_int2(meta, __float_as_int(v_[k]));
    }
  }
}

// ---------------------------------------------------------------------------
// Pass C: one block per bucket -> row_ptr + exact CSR order.
__global__ __launch_bounds__(512) void csr_build_kernel(
    const int2* __restrict__ bucketed, const int* __restrict__ bucket_base,
    int* __restrict__ row_ptr, int2* __restrict__ packed) {
  __shared__ int hist[512], cur[512], sA[512], sB[512];
  const int t = threadIdx.x;
  const int blk = blockIdx.x;
  const int base = bucket_base[blk];
  const int n = bucket_base[blk + 1] - base;

  hist[t] = 0;
  __syncthreads();
  for (int i = t; i < n; i += 512) {
    const int rlow = bucketed[base + i].x >> 17;
    atomicAdd(&hist[rlow], 1);
  }
  __syncthreads();

  sA[t] = hist[t];
  __syncthreads();
  int* src = sA;
  int* dst = sB;
  for (int off = 1; off < 512; off <<= 1) {
    dst[t] = src[t] + ((t >= off) ? src[t - off] : 0);
    __syncthreads();
    int* tmp = src; src = dst; dst = tmp;
  }
  const int excl = src[t] - hist[t];

  const int row0 = blk << 9;
  if (row0 + t < N_NODES) row_ptr[row0 + t] = base + excl;
  if (blk == NBUCK - 1 && t == 0) row_ptr[N_NODES] = N_EDGES;
  cur[t] = excl;
  __syncthreads();

  for (int i = t; i < n; i += 512) {
    const int2 m = bucketed[base + i];
    const int rlow = m.x >> 17;
    const int col = m.x & 0x1FFFF;
    const int p = atomicAdd(&cur[rlow], 1);
    packed[base + p] = make_int2(col, m.y);
  }
}

// ---------------------------------------------------------------------------
// Gather SpMM, fp16 ego table — NO LDS. One wave per node.
template <int DIN>
__global__ __launch_bounds__(512) void spmm_kernel(
    const __half* __restrict__ ego_h, const int* __restrict__ row_ptr,
    const long long* __restrict__ packed, __half* __restrict__ side_out_h) {
  constexpr int LPH = DIN / 8;    // lanes per edge-row (16B fp16 chunks)
  constexpr int NGRP = 64 / LPH;  // edges concurrent

  const int lane = threadIdx.x & 63;
  const int li = lane % LPH;
  const int grp = lane / LPH;
  const int node = (blockIdx.x * blockDim.x + threadIdx.x) >> 6;
  if (node >= N_NODES) return;

  const uint4* __restrict__ ego8 = (const uint4*)ego_h;
  const int start = row_ptr[node];
  const int end = row_ptr[node + 1];

  float s[8] = {0.f, 0.f, 0.f, 0.f, 0.f, 0.f, 0.f, 0.f};

  for (int base = start; base < end; base += 64) {
    const int idx = base + lane;
    long long m = 0;  // col=0, val=0 padding contributes 0
    if (idx < end) m = __builtin_nontemporal_load(packed + idx);
    int mc = (int)m;
    int mv = (int)(m >> 32);
    const int cnt = min(end - base, 64);
    const int kmax = (cnt + NGRP - 1) / NGRP;
    for (int k = 0; k < kmax; ++k) {
      const int src = k * NGRP + grp;
      const int c = __shfl(mc, src, 64);
      const float v = __int_as_float(__shfl(mv, src, 64));
      uint4 raw = ego8[(long)c * LPH + li];
      const __half2* hp = (const __half2*)&raw;
      const float2 f0 = __half22float2(hp[0]);
      const float2 f1 = __half22float2(hp[1]);
      const float2 f2 = __half22float2(hp[2]);
      const float2 f3 = __half22float2(hp[3]);
      s[0] += v * f0.x; s[1] += v * f0.y;
      s[2] += v * f1.x; s[3] += v * f1.y;
      s[4] += v * f2.x; s[5] += v * f2.y;
      s[6] += v * f3.x; s[7] += v * f3.y;
    }
  }

#pragma unroll
  for (int mask = LPH; mask < 64; mask <<= 1) {
#pragma unroll
    for (int r = 0; r < 8; ++r) s[r] += __shfl_xor(s[r], mask, 64);
  }

  if (grp == 0) {
    __half2 p0 = __floats2half2_rn(s[0], s[1]);
    __half2 p1 = __floats2half2_rn(s[2], s[3]);
    __half2 p2 = __floats2half2_rn(s[4], s[5]);
    __half2 p3 = __floats2half2_rn(s[6], s[7]);
    uint4 u;
    u.x = *(unsigned int*)&p0;
    u.y = *(unsigned int*)&p1;
    u.z = *(unsigned int*)&p2;
    u.w = *(unsigned int*)&p3;
    ((uint4*)side_out_h)[(long)node * LPH + li] = u;
  }
}

// ---------------------------------------------------------------------------
// Dense + LN + l2norm, v3: LDS gang staging.
// v1 (130us) was latency-bound: 16 uniform loads/node + non-resident weights
// (52 VGPR). v2's register prefetch spilled to scratch (1.8 GB HBM traffic).
// v3: per-wave gang staging through LDS:
//  - gang of G nodes loaded cooperatively (1 uint4 ego + 1 uint4 side per
//    lane, fully coalesced; only 8 staging VGPRs -> no spill risk),
//  - xs/xp computed ONCE per node at stage time (v1 recomputed x64 lanes),
//  - next gang's global loads issued before the dot passes (latency hidden
//    under ~1600 cy of compute), same-wave LDS so NO __syncthreads needed,
//  - dot passes read LDS uniformly (broadcast, conflict-free),
//  - __launch_bounds__(256,3): 170-VGPR budget, 64 weight regs stay resident.
template <int DIN, int DOUT, int COL_OFF>
__global__ __launch_bounds__(256, 3) void dense_kernel(
    const __half* __restrict__ ego_h, const __half* __restrict__ side_h,
    const __half* __restrict__ w1t, const float* __restrict__ b1,
    const __half* __restrict__ w2t, const float* __restrict__ b2,
    const float* __restrict__ g1, const float* __restrict__ be1,
    const float* __restrict__ g2, const float* __restrict__ be2,
    __half* __restrict__ ego_h_out, float* __restrict__ out) {
  constexpr int CH = DIN / 8;      // uint4 chunks per node row
  constexpr int G = 64 / CH;       // nodes per staged gang
  constexpr int NPW = 64 / DOUT;   // nodes per dot pass
  constexpr int PASSES = G / NPW;  // dot passes per gang

  const int lane = threadIdx.x & 63;
  const int w = threadIdx.x >> 6;
  const int j = lane % DOUT;
  const int sub = lane / DOUT;
  const int sn = lane / CH;  // node-in-gang this lane stages
  const int sc = lane % CH;  // chunk-in-node this lane stages

  // [wave][xs|xp][G*CH slots] = 4*2*64*16B = 8 KB
  __shared__ uint4 lds[4][2][64];

  // resident transposed weights: row j = CH uint4s
  const uint4* __restrict__ w1u = (const uint4*)w1t;
  const uint4* __restrict__ w2u = (const uint4*)w2t;
  uint4 wraw1[CH], wraw2[CH];
#pragma unroll
  for (int q = 0; q < CH; ++q) {
    wraw1[q] = w1u[j * CH + q];
    wraw2[q] = w2u[j * CH + q];
  }
  const float bb1 = b1[j], bb2 = b2[j];
  const float gg1 = g1[j], gg2 = g2[j];
  const float bbe1 = be1[j], bbe2 = be2[j];

  const uint4* __restrict__ ego8 = (const uint4*)ego_h;
  const uint4* __restrict__ side8 = (const uint4*)side_h;

  const int waveId = (blockIdx.x * blockDim.x + threadIdx.x) >> 6;
  const int nwaves = (gridDim.x * blockDim.x) >> 6;
  const int ngangs = N_NODES / G;  // exact: 100000 % {8,16} == 0

  uint4 eR, sR;
  if (waveId < ngangs) {
    const size_t b = (size_t)(waveId * G + sn) * CH + sc;
    eR = ego8[b];
    sR = side8[b];
  }

  for (int gang = waveId; gang < ngangs; gang += nwaves) {
    // ---- stage: xs/xp once per node, write to this wave's LDS slab ----
    uint4 xsU, xpU;
    {
      const h2* e2 = (const h2*)&eR;
      const h2* s2 = (const h2*)&sR;
      h2* xs2 = (h2*)&xsU;
      h2* xp2 = (h2*)&xpU;
#pragma unroll
      for (int r = 0; r < 4; ++r) {
        xs2[r] = e2[r] + s2[r];
        xp2[r] = e2[r] * s2[r];
      }
    }
    // prior gang's ds_reads fully retired before overwriting the slab
    asm volatile("s_waitcnt lgkmcnt(0)" ::: "memory");
    __builtin_amdgcn_sched_barrier(0);
    lds[w][0][lane] = xsU;
    lds[w][1][lane] = xpU;

    // ---- prefetch next gang into the 8 staging VGPRs (no wait) ----
    const int gn = gang + nwaves;
    if (gn < ngangs) {
      const size_t b = (size_t)(gn * G + sn) * CH + sc;
      eR = ego8[b];
      sR = side8[b];
    }

    // ds_writes visible to all lanes of this wave before the reads
    asm volatile("s_waitcnt lgkmcnt(0)" ::: "memory");
    __builtin_amdgcn_sched_barrier(0);

    // ---- dot passes: uniform LDS reads (broadcast), resident weights ----
#pragma unroll
    for (int p = 0; p < PASSES; ++p) {
      const int nin = p * NPW + sub;
      const int node = gang * G + nin;

      float a1a = bb1, a1b = 0.f, a2a = bb2, a2b = 0.f;
#pragma unroll
      for (int q = 0; q < CH; ++q) {
        uint4 xsq = lds[w][0][nin * CH + q];
        uint4 xpq = lds[w][1][nin * CH + q];
        const h2* xs2 = (const h2*)&xsq;
        const h2* xp2 = (const h2*)&xpq;
        const h2* wq1 = (const h2*)&wraw1[q];
        const h2* wq2 = (const h2*)&wraw2[q];
#pragma unroll
        for (int r = 0; r < 4; ++r) {
#if __has_builtin(__builtin_amdgcn_fdot2)
          if (q & 1) {
            a1b = __builtin_amdgcn_fdot2(xs2[r], wq1[r], a1b, false);
            a2b = __builtin_amdgcn_fdot2(xp2[r], wq2[r], a2b, false);
          } else {
            a1a = __builtin_amdgcn_fdot2(xs2[r], wq1[r], a1a, false);
            a2a = __builtin_amdgcn_fdot2(xp2[r], wq2[r], a2a, false);
          }
#else
          if (q & 1) {
            a1b += (float)xs2[r].x * (float)wq1[r].x +
                   (float)xs2[r].y * (float)wq1[r].y;
            a2b += (float)xp2[r].x * (float)wq2[r].x +
                   (float)xp2[r].y * (float)wq2[r].y;
          } else {
            a1a += (float)xs2[r].x * (float)wq1[r].x +
                   (float)xs2[r].y * (float)wq1[r].y;
            a2a += (float)xp2[r].x * (float)wq2[r].x +
                   (float)xp2[r].y * (float)wq2[r].y;
          }
#endif
        }
      }

      const float acc1 = a1a + a1b;
      const float acc2 = a2a + a2b;
      const float h1 = acc1 > 0.f ? acc1 : 0.01f * acc1;
      const float h2v = acc2 > 0.f ? acc2 : 0.01f * acc2;

      // single-pass LN: sum + sumsq, 4 interleaved chains, depth log2(DOUT)
      float s1 = h1, q1 = h1 * h1, s2 = h2v, q2 = h2v * h2v;
#pragma unroll
      for (int mask = DOUT / 2; mask > 0; mask >>= 1) {
        s1 += __shfl_xor(s1, mask, DOUT);
        q1 += __shfl_xor(q1, mask, DOUT);
        s2 += __shfl_xor(s2, mask, DOUT);
        q2 += __shfl_xor(q2, mask, DOUT);
      }
      const float m1 = s1 * (1.0f / DOUT);
      const float m2 = s2 * (1.0f / DOUT);
      const float v1 = fmaxf(q1 * (1.0f / DOUT) - m1 * m1, 0.f);
      const float v2 = fmaxf(q2 * (1.0f / DOUT) - m2 * m2, 0.f);
      const float sv = (h1 - m1) * rsqrtf(v1 + LN_EPS) * gg1 + bbe1;
      const float bv = (h2v - m2) * rsqrtf(v2 + LN_EPS) * gg2 + bbe2;
      const float en = sv + bv;

      float ss = en * en;
#pragma unroll
      for (int mask = DOUT / 2; mask > 0; mask >>= 1) {
        ss += __shfl_xor(ss, mask, DOUT);
      }
      const float ov = en / fmaxf(sqrtf(ss), 1e-12f);

      if (ego_h_out) ego_h_out[(long)node * DOUT + j] = __float2half(en);
      out[(long)node * OUT_DIM + COL_OFF + j] = ov;
    }
  }
}

// ---------------------------------------------------------------------------
extern "C" void kernel_launch(void* const* d_in, const int* in_sizes, int n_in,
                              void* d_out, int out_size, void* d_ws,
                              size_t ws_size, hipStream_t stream) {
  const float* emb = (const float*)d_in[0];
  const int* rows = (const int*)d_in[1];
  const int* cols = (const int*)d_in[2];
  const float* vals = (const float*)d_in[3];

  const float* P[3][8];
  for (int k = 0; k < 3; ++k)
    for (int p = 0; p < 8; ++p) P[k][p] = (const float*)d_in[4 + 8 * k + p];

  float* out = (float*)d_out;

  char* ws = (char*)d_ws;
  int2* packed = (int2*)ws;                          // E*8   = 25.6 MB
  char* sideArea = ws + (size_t)N_EDGES * 8;         // 25.6 MB region
  __half* side_h = (__half*)sideArea;                // N*64*2 = 12.8 MB used
  int2* bucketed = (int2*)sideArea;  // ALIAS: dead before spmm writes side
  __half* emb_h = (__half*)(sideArea + (size_t)N_NODES * 64 * 4);  // 12.8 MB
  __half* ego1_h = emb_h + (size_t)N_NODES * 64;                   // 12.8 MB
  __half* ego2_h = ego1_h + (size_t)N_NODES * 64;                  // 6.4 MB
  // transposed fp16 weights (16B-aligned block)
  __half* wt1_0 = ego2_h + (size_t)N_NODES * 32;  // 4096 halves
  __half* wt2_0 = wt1_0 + 4096;
  __half* wt1_1 = wt2_0 + 4096;  // 2048
  __half* wt2_1 = wt1_1 + 2048;
  __half* wt1_2 = wt2_1 + 2048;  // 512
  __half* wt2_2 = wt1_2 + 512;
  int* row_ptr = (int*)(wt2_2 + 512);  // N+1
  int* gcount = row_ptr + (N_NODES + 1);
  int* bucket_base = gcount + NBUCK;
  int* bucket_cursor = bucket_base + (NBUCK + 1);

  // ---- CSR build via two-level bucket sort ----
  hipMemsetAsync(gcount, 0, NBUCK * sizeof(int), stream);
  precount_kernel<<<PC_BLOCKS, 256, 0, stream>>>(rows, gcount);
  bucket_scan_kernel<<<1, 256, 0, stream>>>(gcount, bucket_base,
                                            bucket_cursor);
  bucket_pass_kernel<<<BP_BLOCKS, 256, 0, stream>>>(rows, cols, vals,
                                                    bucket_cursor, bucketed);
  csr_build_kernel<<<NBUCK, 512, 0, stream>>>(bucketed, bucket_base, row_ptr,
                                              packed);

  // ---- weight prep (transposed fp16) ----
  wprep_kernel<<<16, 256, 0, stream>>>(P[0][0], P[0][2], wt1_0, wt2_0, 64, 64);
  wprep_kernel<<<8, 256, 0, stream>>>(P[1][0], P[1][2], wt1_1, wt2_1, 64, 32);
  wprep_kernel<<<2, 256, 0, stream>>>(P[2][0], P[2][2], wt1_2, wt2_2, 32, 16);

  convert_emb_kernel<<<(N_NODES * 16 + 255) / 256, 256, 0, stream>>>(emb, out,
                                                                     emb_h);

  const int SPMM_BLOCKS = (N_NODES + 7) / 8;  // wave/node, 512 threads
  const int DENSE_BLOCKS = 1024;              // 4 blocks/CU, 8 KB LDS each

  // ---- layer 0: 64 -> 64 ----
  spmm_kernel<64><<<SPMM_BLOCKS, 512, 0, stream>>>(
      emb_h, row_ptr, (const long long*)packed, side_h);
  dense_kernel<64, 64, 64><<<DENSE_BLOCKS, 256, 0, stream>>>(
      emb_h, side_h, wt1_0, P[0][1], wt2_0, P[0][3], P[0][4], P[0][5],
      P[0][6], P[0][7], ego1_h, out);

  // ---- layer 1: 64 -> 32 ----
  spmm_kernel<64><<<SPMM_BLOCKS, 512, 0, stream>>>(
      ego1_h, row_ptr, (const long long*)packed, side_h);
  dense_kernel<64, 32, 128><<<DENSE_BLOCKS, 256, 0, stream>>>(
      ego1_h, side_h, wt1_1, P[1][1], wt2_1, P[1][3], P[1][4], P[1][5],
      P[1][6], P[1][7], ego2_h, out);

  // ---- layer 2: 32 -> 16 ----
  spmm_kernel<32><<<SPMM_BLOCKS, 512, 0, stream>>>(
      ego2_h, row_ptr, (const long long*)packed, side_h);
  dense_kernel<32, 16, 160><<<DENSE_BLOCKS, 256, 0, stream>>>(
      ego2_h, side_h, wt1_2, P[2][1], wt2_2, P[2][3], P[2][4], P[2][5],
      P[2][6], P[2][7], nullptr, out);
}

// Round 3
// 536.118 us; speedup vs baseline: 2.0682x; 1.0125x over previous
//
#include <hip/hip_runtime.h>
#include <hip/hip_fp16.h>

#define N_NODES 100000
#define N_EDGES 3200000
#define OUT_DIM 176
#define LN_EPS 1e-5f

typedef _Float16 h2 __attribute__((ext_vector_type(2)));

// Bucket sort parameters: bucket = row >> 9 (512 rows/bucket)
#define NBUCK 196
#define PC_BLOCKS 512
#define PC_CHUNK (N_EDGES / PC_BLOCKS)  // 6250
#define BP_CHUNK 4096
#define BP_BLOCKS ((N_EDGES + BP_CHUNK - 1) / BP_CHUNK)  // 782

// ---------------------------------------------------------------------------
// out[:, 0:64] = emb (fp32) AND emb_h = fp16(emb).
__global__ __launch_bounds__(256) void convert_emb_kernel(
    const float* __restrict__ emb, float* __restrict__ out,
    __half* __restrict__ emb_h) {
  int t = blockIdx.x * blockDim.x + threadIdx.x;
  if (t < N_NODES * 16) {
    int n = t >> 4, q = t & 15;
    float4 v = ((const float4*)emb)[t];
    ((float4*)out)[n * 44 + q] = v;
    __half2 a = __floats2half2_rn(v.x, v.y);
    __half2 b = __floats2half2_rn(v.z, v.w);
    uint2 u;
    u.x = *(unsigned int*)&a;
    u.y = *(unsigned int*)&b;
    ((uint2*)emb_h)[t] = u;
  }
}

// ---------------------------------------------------------------------------
// Fused weight prep for all 3 layers: wt[j*DIN+i] = (half)w[i*DOUT+j].
// Ranges: L0 2x 64*64=4096, L1 2x 64*32=2048, L2 2x 32*16=512 -> 6656 elems.
__global__ __launch_bounds__(256) void wprep_all_kernel(
    const float* __restrict__ w1_0, const float* __restrict__ w2_0,
    const float* __restrict__ w1_1, const float* __restrict__ w2_1,
    const float* __restrict__ w1_2, const float* __restrict__ w2_2,
    __half* __restrict__ wt1_0, __half* __restrict__ wt2_0,
    __half* __restrict__ wt1_1, __half* __restrict__ wt2_1,
    __half* __restrict__ wt1_2, __half* __restrict__ wt2_2) {
  int idx = blockIdx.x * 256 + threadIdx.x;
  const float* w1;
  const float* w2;
  __half* t1;
  __half* t2;
  int din, dout;
  if (idx < 4096) {
    w1 = w1_0; w2 = w2_0; t1 = wt1_0; t2 = wt2_0; din = 64; dout = 64;
  } else if (idx < 4096 + 2048) {
    idx -= 4096;
    w1 = w1_1; w2 = w2_1; t1 = wt1_1; t2 = wt2_1; din = 64; dout = 32;
  } else if (idx < 4096 + 2048 + 512) {
    idx -= 4096 + 2048;
    w1 = w1_2; w2 = w2_2; t1 = wt1_2; t2 = wt2_2; din = 32; dout = 16;
  } else {
    return;
  }
  int i = idx / dout, j = idx % dout;
  t1[j * din + i] = __float2half(w1[idx]);
  t2[j * din + i] = __float2half(w2[idx]);
}

// ---------------------------------------------------------------------------
// Pass A: per-bucket edge counts.
__global__ __launch_bounds__(256) void precount_kernel(
    const int* __restrict__ rows, int* __restrict__ gcount) {
  __shared__ int hist[NBUCK];
  for (int i = threadIdx.x; i < NBUCK; i += 256) hist[i] = 0;
  __syncthreads();
  const int e0 = blockIdx.x * PC_CHUNK;
  for (int e = e0 + threadIdx.x; e < e0 + PC_CHUNK; e += 256) {
    const int r = __builtin_nontemporal_load(rows + e);
    atomicAdd(&hist[r >> 9], 1);
  }
  __syncthreads();
  for (int i = threadIdx.x; i < NBUCK; i += 256)
    if (hist[i]) atomicAdd(&gcount[i], hist[i]);
}

// Exclusive scan of bucket counts -> bucket_base[197], cursor copy.
__global__ __launch_bounds__(256) void bucket_scan_kernel(
    const int* __restrict__ gcount, int* __restrict__ bucket_base,
    int* __restrict__ bucket_cursor) {
  __shared__ int sA[256], sB[256];
  const int t = threadIdx.x;
  int v = (t < NBUCK) ? gcount[t] : 0;
  sA[t] = v;
  __syncthreads();
  int* src = sA;
  int* dst = sB;
  for (int off = 1; off < 256; off <<= 1) {
    dst[t] = src[t] + ((t >= off) ? src[t - off] : 0);
    __syncthreads();
    int* tmp = src; src = dst; dst = tmp;
  }
  if (t < NBUCK) {
    const int excl = src[t] - v;
    bucket_base[t] = excl;
    bucket_cursor[t] = excl;
  }
  if (t == 0) bucket_base[NBUCK] = N_EDGES;
}

// ---------------------------------------------------------------------------
// Pass B: bucket the edges.
__global__ __launch_bounds__(256) void bucket_pass_kernel(
    const int* __restrict__ rows, const int* __restrict__ cols,
    const float* __restrict__ vals, int* __restrict__ bucket_cursor,
    int2* __restrict__ bucketed) {
  __shared__ int cnt[NBUCK], cur[NBUCK], gbase[NBUCK];
  for (int i = threadIdx.x; i < NBUCK; i += 256) {
    cnt[i] = 0;
    cur[i] = 0;
  }
  __syncthreads();

  const int e0 = blockIdx.x * BP_CHUNK;
  int r_[16], c_[16];
  float v_[16];
#pragma unroll
  for (int k = 0; k < 16; ++k) {
    const int e = e0 + threadIdx.x + k * 256;
    if (e < N_EDGES) {
      r_[k] = rows[e];
      c_[k] = cols[e];
      v_[k] = vals[e];
      atomicAdd(&cnt[r_[k] >> 9], 1);
    } else {
      r_[k] = -1;
    }
  }
  __syncthreads();

  for (int i = threadIdx.x; i < NBUCK; i += 256)
    gbase[i] = cnt[i] ? atomicAdd(&bucket_cursor[i], cnt[i]) : 0;
  __syncthreads();

#pragma unroll
  for (int k = 0; k < 16; ++k) {
    if (r_[k] >= 0) {
      const int b = r_[k] >> 9;
      const int lp = atomicAdd(&cur[b], 1);
      const int meta = c_[k] | ((r_[k] & 511) << 17);
      bucketed[gbase[b] + lp] = make_int2(meta, __float_as_int(v_[k]));
    }
  }
}

// ---------------------------------------------------------------------------
// Pass C: one block per bucket -> row_ptr + exact CSR order.
__global__ __launch_bounds__(512) void csr_build_kernel(
    const int2* __restrict__ bucketed, const int* __restrict__ bucket_base,
    int* __restrict__ row_ptr, int2* __restrict__ packed) {
  __shared__ int hist[512], cur[512], sA[512], sB[512];
  const int t = threadIdx.x;
  const int blk = blockIdx.x;
  const int base = bucket_base[blk];
  const int n = bucket_base[blk + 1] - base;

  hist[t] = 0;
  __syncthreads();
  for (int i = t; i < n; i += 512) {
    const int rlow = bucketed[base + i].x >> 17;
    atomicAdd(&hist[rlow], 1);
  }
  __syncthreads();

  sA[t] = hist[t];
  __syncthreads();
  int* src = sA;
  int* dst = sB;
  for (int off = 1; off < 512; off <<= 1) {
    dst[t] = src[t] + ((t >= off) ? src[t - off] : 0);
    __syncthreads();
    int* tmp = src; src = dst; dst = tmp;
  }
  const int excl = src[t] - hist[t];

  const int row0 = blk << 9;
  if (row0 + t < N_NODES) row_ptr[row0 + t] = base + excl;
  if (blk == NBUCK - 1 && t == 0) row_ptr[N_NODES] = N_EDGES;
  cur[t] = excl;
  __syncthreads();

  for (int i = t; i < n; i += 512) {
    const int2 m = bucketed[base + i];
    const int rlow = m.x >> 17;
    const int col = m.x & 0x1FFFF;
    const int p = atomicAdd(&cur[rlow], 1);
    packed[base + p] = make_int2(col, m.y);
  }
}

// ---------------------------------------------------------------------------
// Gather SpMM, fp16 ego table — NO LDS. One wave per node.
template <int DIN>
__global__ __launch_bounds__(512) void spmm_kernel(
    const __half* __restrict__ ego_h, const int* __restrict__ row_ptr,
    const long long* __restrict__ packed, __half* __restrict__ side_out_h) {
  constexpr int LPH = DIN / 8;    // lanes per edge-row (16B fp16 chunks)
  constexpr int NGRP = 64 / LPH;  // edges concurrent

  const int lane = threadIdx.x & 63;
  const int li = lane % LPH;
  const int grp = lane / LPH;
  const int node = (blockIdx.x * blockDim.x + threadIdx.x) >> 6;
  if (node >= N_NODES) return;

  const uint4* __restrict__ ego8 = (const uint4*)ego_h;
  const int start = row_ptr[node];
  const int end = row_ptr[node + 1];

  float s[8] = {0.f, 0.f, 0.f, 0.f, 0.f, 0.f, 0.f, 0.f};

  for (int base = start; base < end; base += 64) {
    const int idx = base + lane;
    long long m = 0;  // col=0, val=0 padding contributes 0
    if (idx < end) m = __builtin_nontemporal_load(packed + idx);
    int mc = (int)m;
    int mv = (int)(m >> 32);
    const int cnt = min(end - base, 64);
    const int kmax = (cnt + NGRP - 1) / NGRP;
    for (int k = 0; k < kmax; ++k) {
      const int src = k * NGRP + grp;
      const int c = __shfl(mc, src, 64);
      const float v = __int_as_float(__shfl(mv, src, 64));
      uint4 raw = ego8[(long)c * LPH + li];
      const __half2* hp = (const __half2*)&raw;
      const float2 f0 = __half22float2(hp[0]);
      const float2 f1 = __half22float2(hp[1]);
      const float2 f2 = __half22float2(hp[2]);
      const float2 f3 = __half22float2(hp[3]);
      s[0] += v * f0.x; s[1] += v * f0.y;
      s[2] += v * f1.x; s[3] += v * f1.y;
      s[4] += v * f2.x; s[5] += v * f2.y;
      s[6] += v * f3.x; s[7] += v * f3.y;
    }
  }

#pragma unroll
  for (int mask = LPH; mask < 64; mask <<= 1) {
#pragma unroll
    for (int r = 0; r < 8; ++r) s[r] += __shfl_xor(s[r], mask, 64);
  }

  if (grp == 0) {
    __half2 p0 = __floats2half2_rn(s[0], s[1]);
    __half2 p1 = __floats2half2_rn(s[2], s[3]);
    __half2 p2 = __floats2half2_rn(s[4], s[5]);
    __half2 p3 = __floats2half2_rn(s[6], s[7]);
    uint4 u;
    u.x = *(unsigned int*)&p0;
    u.y = *(unsigned int*)&p1;
    u.z = *(unsigned int*)&p2;
    u.w = *(unsigned int*)&p3;
    ((uint4*)side_out_h)[(long)node * LPH + li] = u;
  }
}

// ---------------------------------------------------------------------------
// Dense + LN + l2norm, v4: v3's LDS gang staging + full occupancy.
// v3 counters: VGPR=64, LDS=8KB -> HW capacity 8 blocks/CU, but grid 1024
// gave only 4/CU (OccupancyPercent 30, VALUBusy 41 -> latency-bound on the
// shfl/LDS chains). v4: grid 2048 (all 8 blocks/CU resident) so the LN
// shfl-chain stalls of one gang overlap another gang's fdot2 phase.
template <int DIN, int DOUT, int COL_OFF>
__global__ __launch_bounds__(256, 4) void dense_kernel(
    const __half* __restrict__ ego_h, const __half* __restrict__ side_h,
    const __half* __restrict__ w1t, const float* __restrict__ b1,
    const __half* __restrict__ w2t, const float* __restrict__ b2,
    const float* __restrict__ g1, const float* __restrict__ be1,
    const float* __restrict__ g2, const float* __restrict__ be2,
    __half* __restrict__ ego_h_out, float* __restrict__ out) {
  constexpr int CH = DIN / 8;      // uint4 chunks per node row
  constexpr int G = 64 / CH;       // nodes per staged gang
  constexpr int NPW = 64 / DOUT;   // nodes per dot pass
  constexpr int PASSES = G / NPW;  // dot passes per gang

  const int lane = threadIdx.x & 63;
  const int w = threadIdx.x >> 6;
  const int j = lane % DOUT;
  const int sub = lane / DOUT;
  const int sn = lane / CH;  // node-in-gang this lane stages
  const int sc = lane % CH;  // chunk-in-node this lane stages

  // [wave][xs|xp][G*CH slots] = 4*2*64*16B = 8 KB
  __shared__ uint4 lds[4][2][64];

  // resident transposed weights: row j = CH uint4s
  const uint4* __restrict__ w1u = (const uint4*)w1t;
  const uint4* __restrict__ w2u = (const uint4*)w2t;
  uint4 wraw1[CH], wraw2[CH];
#pragma unroll
  for (int q = 0; q < CH; ++q) {
    wraw1[q] = w1u[j * CH + q];
    wraw2[q] = w2u[j * CH + q];
  }
  const float bb1 = b1[j], bb2 = b2[j];
  const float gg1 = g1[j], gg2 = g2[j];
  const float bbe1 = be1[j], bbe2 = be2[j];

  const uint4* __restrict__ ego8 = (const uint4*)ego_h;
  const uint4* __restrict__ side8 = (const uint4*)side_h;

  const int waveId = (blockIdx.x * blockDim.x + threadIdx.x) >> 6;
  const int nwaves = (gridDim.x * blockDim.x) >> 6;
  const int ngangs = N_NODES / G;  // exact: 100000 % {8,16} == 0

  uint4 eR, sR;
  if (waveId < ngangs) {
    const size_t b = (size_t)(waveId * G + sn) * CH + sc;
    eR = ego8[b];
    sR = side8[b];
  }

  for (int gang = waveId; gang < ngangs; gang += nwaves) {
    // ---- stage: xs/xp once per node, write to this wave's LDS slab ----
    uint4 xsU, xpU;
    {
      const h2* e2 = (const h2*)&eR;
      const h2* s2 = (const h2*)&sR;
      h2* xs2 = (h2*)&xsU;
      h2* xp2 = (h2*)&xpU;
#pragma unroll
      for (int r = 0; r < 4; ++r) {
        xs2[r] = e2[r] + s2[r];
        xp2[r] = e2[r] * s2[r];
      }
    }
    // prior gang's ds_reads fully retired before overwriting the slab
    asm volatile("s_waitcnt lgkmcnt(0)" ::: "memory");
    __builtin_amdgcn_sched_barrier(0);
    lds[w][0][lane] = xsU;
    lds[w][1][lane] = xpU;

    // ---- prefetch next gang into the 8 staging VGPRs (no wait) ----
    const int gn = gang + nwaves;
    if (gn < ngangs) {
      const size_t b = (size_t)(gn * G + sn) * CH + sc;
      eR = ego8[b];
      sR = side8[b];
    }

    // ds_writes visible to all lanes of this wave before the reads
    asm volatile("s_waitcnt lgkmcnt(0)" ::: "memory");
    __builtin_amdgcn_sched_barrier(0);

    // ---- dot passes: uniform LDS reads (broadcast), resident weights ----
#pragma unroll
    for (int p = 0; p < PASSES; ++p) {
      const int nin = p * NPW + sub;
      const int node = gang * G + nin;

      float a1a = bb1, a1b = 0.f, a2a = bb2, a2b = 0.f;
#pragma unroll
      for (int q = 0; q < CH; ++q) {
        uint4 xsq = lds[w][0][nin * CH + q];
        uint4 xpq = lds[w][1][nin * CH + q];
        const h2* xs2 = (const h2*)&xsq;
        const h2* xp2 = (const h2*)&xpq;
        const h2* wq1 = (const h2*)&wraw1[q];
        const h2* wq2 = (const h2*)&wraw2[q];
#pragma unroll
        for (int r = 0; r < 4; ++r) {
#if __has_builtin(__builtin_amdgcn_fdot2)
          if (q & 1) {
            a1b = __builtin_amdgcn_fdot2(xs2[r], wq1[r], a1b, false);
            a2b = __builtin_amdgcn_fdot2(xp2[r], wq2[r], a2b, false);
          } else {
            a1a = __builtin_amdgcn_fdot2(xs2[r], wq1[r], a1a, false);
            a2a = __builtin_amdgcn_fdot2(xp2[r], wq2[r], a2a, false);
          }
#else
          if (q & 1) {
            a1b += (float)xs2[r].x * (float)wq1[r].x +
                   (float)xs2[r].y * (float)wq1[r].y;
            a2b += (float)xp2[r].x * (float)wq2[r].x +
                   (float)xp2[r].y * (float)wq2[r].y;
          } else {
            a1a += (float)xs2[r].x * (float)wq1[r].x +
                   (float)xs2[r].y * (float)wq1[r].y;
            a2a += (float)xp2[r].x * (float)wq2[r].x +
                   (float)xp2[r].y * (float)wq2[r].y;
          }
#endif
        }
      }

      const float acc1 = a1a + a1b;
      const float acc2 = a2a + a2b;
      const float h1 = acc1 > 0.f ? acc1 : 0.01f * acc1;
      const float h2v = acc2 > 0.f ? acc2 : 0.01f * acc2;

      // single-pass LN: sum + sumsq, 4 interleaved chains, depth log2(DOUT)
      float s1 = h1, q1 = h1 * h1, s2 = h2v, q2 = h2v * h2v;
#pragma unroll
      for (int mask = DOUT / 2; mask > 0; mask >>= 1) {
        s1 += __shfl_xor(s1, mask, DOUT);
        q1 += __shfl_xor(q1, mask, DOUT);
        s2 += __shfl_xor(s2, mask, DOUT);
        q2 += __shfl_xor(q2, mask, DOUT);
      }
      const float m1 = s1 * (1.0f / DOUT);
      const float m2 = s2 * (1.0f / DOUT);
      const float v1 = fmaxf(q1 * (1.0f / DOUT) - m1 * m1, 0.f);
      const float v2 = fmaxf(q2 * (1.0f / DOUT) - m2 * m2, 0.f);
      const float sv = (h1 - m1) * rsqrtf(v1 + LN_EPS) * gg1 + bbe1;
      const float bv = (h2v - m2) * rsqrtf(v2 + LN_EPS) * gg2 + bbe2;
      const float en = sv + bv;

      float ss = en * en;
#pragma unroll
      for (int mask = DOUT / 2; mask > 0; mask >>= 1) {
        ss += __shfl_xor(ss, mask, DOUT);
      }
      const float ov = en / fmaxf(sqrtf(ss), 1e-12f);

      if (ego_h_out) ego_h_out[(long)node * DOUT + j] = __float2half(en);
      out[(long)node * OUT_DIM + COL_OFF + j] = ov;
    }
  }
}

// ---------------------------------------------------------------------------
extern "C" void kernel_launch(void* const* d_in, const int* in_sizes, int n_in,
                              void* d_out, int out_size, void* d_ws,
                              size_t ws_size, hipStream_t stream) {
  const float* emb = (const float*)d_in[0];
  const int* rows = (const int*)d_in[1];
  const int* cols = (const int*)d_in[2];
  const float* vals = (const float*)d_in[3];

  const float* P[3][8];
  for (int k = 0; k < 3; ++k)
    for (int p = 0; p < 8; ++p) P[k][p] = (const float*)d_in[4 + 8 * k + p];

  float* out = (float*)d_out;

  char* ws = (char*)d_ws;
  int2* packed = (int2*)ws;                          // E*8   = 25.6 MB
  char* sideArea = ws + (size_t)N_EDGES * 8;         // 25.6 MB region
  __half* side_h = (__half*)sideArea;                // N*64*2 = 12.8 MB used
  int2* bucketed = (int2*)sideArea;  // ALIAS: dead before spmm writes side
  __half* emb_h = (__half*)(sideArea + (size_t)N_NODES * 64 * 4);  // 12.8 MB
  __half* ego1_h = emb_h + (size_t)N_NODES * 64;                   // 12.8 MB
  __half* ego2_h = ego1_h + (size_t)N_NODES * 64;                  // 6.4 MB
  // transposed fp16 weights (16B-aligned block)
  __half* wt1_0 = ego2_h + (size_t)N_NODES * 32;  // 4096 halves
  __half* wt2_0 = wt1_0 + 4096;
  __half* wt1_1 = wt2_0 + 4096;  // 2048
  __half* wt2_1 = wt1_1 + 2048;
  __half* wt1_2 = wt2_1 + 2048;  // 512
  __half* wt2_2 = wt1_2 + 512;
  int* row_ptr = (int*)(wt2_2 + 512);  // N+1
  int* gcount = row_ptr + (N_NODES + 1);
  int* bucket_base = gcount + NBUCK;
  int* bucket_cursor = bucket_base + (NBUCK + 1);

  // ---- CSR build via two-level bucket sort ----
  hipMemsetAsync(gcount, 0, NBUCK * sizeof(int), stream);
  precount_kernel<<<PC_BLOCKS, 256, 0, stream>>>(rows, gcount);
  bucket_scan_kernel<<<1, 256, 0, stream>>>(gcount, bucket_base,
                                            bucket_cursor);
  bucket_pass_kernel<<<BP_BLOCKS, 256, 0, stream>>>(rows, cols, vals,
                                                    bucket_cursor, bucketed);
  csr_build_kernel<<<NBUCK, 512, 0, stream>>>(bucketed, bucket_base, row_ptr,
                                              packed);

  // ---- weight prep (transposed fp16), all 3 layers in one launch ----
  wprep_all_kernel<<<26, 256, 0, stream>>>(P[0][0], P[0][2], P[1][0], P[1][2],
                                           P[2][0], P[2][2], wt1_0, wt2_0,
                                           wt1_1, wt2_1, wt1_2, wt2_2);

  convert_emb_kernel<<<(N_NODES * 16 + 255) / 256, 256, 0, stream>>>(emb, out,
                                                                     emb_h);

  const int SPMM_BLOCKS = (N_NODES + 7) / 8;  // wave/node, 512 threads
  const int DENSE_BLOCKS = 2048;              // 8 blocks/CU, all resident

  // ---- layer 0: 64 -> 64 ----
  spmm_kernel<64><<<SPMM_BLOCKS, 512, 0, stream>>>(
      emb_h, row_ptr, (const long long*)packed, side_h);
  dense_kernel<64, 64, 64><<<DENSE_BLOCKS, 256, 0, stream>>>(
      emb_h, side_h, wt1_0, P[0][1], wt2_0, P[0][3], P[0][4], P[0][5],
      P[0][6], P[0][7], ego1_h, out);

  // ---- layer 1: 64 -> 32 ----
  spmm_kernel<64><<<SPMM_BLOCKS, 512, 0, stream>>>(
      ego1_h, row_ptr, (const long long*)packed, side_h);
  dense_kernel<64, 32, 128><<<DENSE_BLOCKS, 256, 0, stream>>>(
      ego1_h, side_h, wt1_1, P[1][1], wt2_1, P[1][3], P[1][4], P[1][5],
      P[1][6], P[1][7], ego2_h, out);

  // ---- layer 2: 32 -> 16 ----
  spmm_kernel<32><<<SPMM_BLOCKS, 512, 0, stream>>>(
      ego2_h, row_ptr, (const long long*)packed, side_h);
  dense_kernel<32, 16, 160><<<DENSE_BLOCKS, 256, 0, stream>>>(
      ego2_h, side_h, wt1_2, P[2][1], wt2_2, P[2][3], P[2][4], P[2][5],
      P[2][6], P[2][7], nullptr, out);
}